// Round 1
// baseline (2208.079 us; speedup 1.0000x reference)
//
#include <hip/hip_runtime.h>
#include <math.h>

#define SEQ  2048
#define CDIM 2048
#define NH   16
#define DH   128
#define HDIM 2048   // NH * DH

// ---------------------------------------------------------------------------
// GEMM (NT): C[m][n] = sum_k A[m][k] * B[n][k]
// A: M x K row-major, B: N x K row-major (weights are stored [n][c]).
// M = N = K = 2048 (compile-time). blockIdx.z selects which weight slice
// (q/k/v) via bStride/cStride.
// Tile: 64x64, BK=32, 256 threads, 4x4 micro-tile.
// LDS stored transposed ([k][m] / [k][n]) so fragment reads are float4.
// ---------------------------------------------------------------------------
__global__ __launch_bounds__(256) void gemm_nt(const float* __restrict__ A,
                                               const float* __restrict__ B,
                                               float* __restrict__ C,
                                               long bStride, long cStride) {
  constexpr int K = CDIM;
  constexpr int N = HDIM;
  __shared__ float As[32][68];
  __shared__ float Bs[32][68];
  const float* Bp = B + (long)blockIdx.z * bStride;
  float* Cp = C + (long)blockIdx.z * cStride;
  const int m0 = blockIdx.y * 64, n0 = blockIdx.x * 64;
  const int tid = threadIdx.x;
  const int tx = tid & 15, ty = tid >> 4;
  const int lr = tid >> 3;        // 0..31
  const int lc = (tid & 7) * 4;   // 0,4,...,28
  float acc[4][4] = {};
  for (int k0 = 0; k0 < K; k0 += 32) {
    float4 a0 = *(const float4*)&A [(long)(m0 + lr)      * K + k0 + lc];
    float4 a1 = *(const float4*)&A [(long)(m0 + lr + 32) * K + k0 + lc];
    float4 b0 = *(const float4*)&Bp[(long)(n0 + lr)      * K + k0 + lc];
    float4 b1 = *(const float4*)&Bp[(long)(n0 + lr + 32) * K + k0 + lc];
    __syncthreads();  // protect previous iteration's LDS reads
    As[lc + 0][lr] = a0.x; As[lc + 1][lr] = a0.y; As[lc + 2][lr] = a0.z; As[lc + 3][lr] = a0.w;
    As[lc + 0][lr + 32] = a1.x; As[lc + 1][lr + 32] = a1.y; As[lc + 2][lr + 32] = a1.z; As[lc + 3][lr + 32] = a1.w;
    Bs[lc + 0][lr] = b0.x; Bs[lc + 1][lr] = b0.y; Bs[lc + 2][lr] = b0.z; Bs[lc + 3][lr] = b0.w;
    Bs[lc + 0][lr + 32] = b1.x; Bs[lc + 1][lr + 32] = b1.y; Bs[lc + 2][lr + 32] = b1.z; Bs[lc + 3][lr + 32] = b1.w;
    __syncthreads();
#pragma unroll
    for (int kk = 0; kk < 32; ++kk) {
      float4 av = *(const float4*)&As[kk][ty * 4];
      float4 bv = *(const float4*)&Bs[kk][tx * 4];
      acc[0][0] += av.x * bv.x; acc[0][1] += av.x * bv.y; acc[0][2] += av.x * bv.z; acc[0][3] += av.x * bv.w;
      acc[1][0] += av.y * bv.x; acc[1][1] += av.y * bv.y; acc[1][2] += av.y * bv.z; acc[1][3] += av.y * bv.w;
      acc[2][0] += av.z * bv.x; acc[2][1] += av.z * bv.y; acc[2][2] += av.z * bv.z; acc[2][3] += av.z * bv.w;
      acc[3][0] += av.w * bv.x; acc[3][1] += av.w * bv.y; acc[3][2] += av.w * bv.z; acc[3][3] += av.w * bv.w;
    }
  }
#pragma unroll
  for (int i = 0; i < 4; ++i) {
    float4 o;
    o.x = acc[i][0]; o.y = acc[i][1]; o.z = acc[i][2]; o.w = acc[i][3];
    *(float4*)&Cp[(long)(m0 + ty * 4 + i) * N + n0 + tx * 4] = o;
  }
}

// ---------------------------------------------------------------------------
// Per-(t,h) RMSNorm(q,k,v) + RoPE(q,k) + v = l0*v + l1*ve.
// One wave (64 threads) per (t,h); thread d holds elements d and d+64, which
// is exactly the (x1, x2) rotate-half split RoPE needs.
// ---------------------------------------------------------------------------
__device__ __forceinline__ float wave_sum64(float x) {
#pragma unroll
  for (int m = 32; m >= 1; m >>= 1) x += __shfl_xor(x, m, 64);
  return x;
}

__global__ __launch_bounds__(64) void norm_rope_mix(float* __restrict__ qkv,
                                                    const float* __restrict__ ve,
                                                    const float* __restrict__ lambdas) {
  const int t = blockIdx.x;
  const int h = blockIdx.y;
  const int d = threadIdx.x;  // 0..63
  const long base = (long)t * HDIM + h * DH;
  float* q = qkv + base;
  float* k = qkv + (long)SEQ * HDIM + base;
  float* v = qkv + 2L * SEQ * HDIM + base;

  float q1 = q[d], q2 = q[d + 64];
  float k1 = k[d], k2 = k[d + 64];
  float v1 = v[d], v2 = v[d + 64];

  float qss = wave_sum64(q1 * q1 + q2 * q2);
  float kss = wave_sum64(k1 * k1 + k2 * k2);
  float vss = wave_sum64(v1 * v1 + v2 * v2);
  float qsc = rsqrtf(qss * (1.0f / 128.0f) + 1e-6f);
  float ksc = rsqrtf(kss * (1.0f / 128.0f) + 1e-6f);
  float vsc = rsqrtf(vss * (1.0f / 128.0f) + 1e-6f);
  q1 *= qsc; q2 *= qsc;
  k1 *= ksc; k2 *= ksc;
  v1 *= vsc; v2 *= vsc;

  // RoPE tables: freq[d<32] = (1/1024)^(d/31), else 0 (identity half).
  float freq = (d < 32) ? powf(1.0f / 1024.0f, (float)d * (1.0f / 31.0f)) : 0.0f;
  float th = (float)t * freq;
  float c = cosf(th), s = sinf(th);

  float qo1 = q1 * c + q2 * s, qo2 = -q1 * s + q2 * c;
  float ko1 = k1 * c + k2 * s, ko2 = -k1 * s + k2 * c;

  float l0 = lambdas[0], l1 = lambdas[1];
  const float* vep = ve + base;
  float vo1 = l0 * v1 + l1 * vep[d];
  float vo2 = l0 * v2 + l1 * vep[d + 64];

  q[d] = qo1; q[d + 64] = qo2;
  k[d] = ko1; k[d + 64] = ko2;
  v[d] = vo1; v[d + 64] = vo2;
}

// ---------------------------------------------------------------------------
// Causal flash attention. Block = (q-tile of 32 rows, one head), 256 threads.
// K/V staged in 32-row LDS tiles; online softmax; O accumulator in registers.
// Thread (r = tid/8, g = tid%8) owns row r, d-columns [g*16, g*16+16).
// ---------------------------------------------------------------------------
__global__ __launch_bounds__(256) void flash_attn(const float* __restrict__ qkv,
                                                  float* __restrict__ y) {
  __shared__ float Qs[32][132];
  __shared__ float Ks[32][132];
  __shared__ float Vs[32][132];
  __shared__ float Ss[32][33];
  const int qb = blockIdx.x, h = blockIdx.y;
  const int q0 = qb * 32;
  const int tid = threadIdx.x;
  const float* Q  = qkv;
  const float* Kp = qkv + (long)SEQ * HDIM;
  const float* Vp = qkv + 2L * SEQ * HDIM;

  // load Q tile (32 x 128) as float4s
#pragma unroll
  for (int it = 0; it < 4; ++it) {
    int idx = tid + it * 256;
    int row = idx >> 5, c4 = (idx & 31) * 4;
    *(float4*)&Qs[row][c4] = *(const float4*)&Q[(long)(q0 + row) * HDIM + h * DH + c4];
  }

  const int r = tid >> 3, g = tid & 7;
  float4 Of[4] = {};
  float m = -INFINITY, l = 0.0f;

  for (int s0 = 0; s0 <= q0; s0 += 32) {
    __syncthreads();  // prior-iter Ks/Vs/Ss reads done; also fences Q load
#pragma unroll
    for (int it = 0; it < 4; ++it) {
      int idx = tid + it * 256;
      int row = idx >> 5, c4 = (idx & 31) * 4;
      *(float4*)&Ks[row][c4] = *(const float4*)&Kp[(long)(s0 + row) * HDIM + h * DH + c4];
      *(float4*)&Vs[row][c4] = *(const float4*)&Vp[(long)(s0 + row) * HDIM + h * DH + c4];
    }
    __syncthreads();

    // scores: thread computes S[r][g*4 .. g*4+3]
    float acc0 = 0.f, acc1 = 0.f, acc2 = 0.f, acc3 = 0.f;
#pragma unroll 8
    for (int d4 = 0; d4 < 32; ++d4) {
      float4 qv = *(const float4*)&Qs[r][d4 * 4];
      float4 k0v = *(const float4*)&Ks[g * 4 + 0][d4 * 4];
      float4 k1v = *(const float4*)&Ks[g * 4 + 1][d4 * 4];
      float4 k2v = *(const float4*)&Ks[g * 4 + 2][d4 * 4];
      float4 k3v = *(const float4*)&Ks[g * 4 + 3][d4 * 4];
      acc0 += qv.x * k0v.x + qv.y * k0v.y + qv.z * k0v.z + qv.w * k0v.w;
      acc1 += qv.x * k1v.x + qv.y * k1v.y + qv.z * k1v.z + qv.w * k1v.w;
      acc2 += qv.x * k2v.x + qv.y * k2v.y + qv.z * k2v.z + qv.w * k2v.w;
      acc3 += qv.x * k3v.x + qv.y * k3v.y + qv.z * k3v.z + qv.w * k3v.w;
    }
    const int t = q0 + r;
    Ss[r][g * 4 + 0] = (s0 + g * 4 + 0 <= t) ? acc0 * 0.12f : -INFINITY;
    Ss[r][g * 4 + 1] = (s0 + g * 4 + 1 <= t) ? acc1 * 0.12f : -INFINITY;
    Ss[r][g * 4 + 2] = (s0 + g * 4 + 2 <= t) ? acc2 * 0.12f : -INFINITY;
    Ss[r][g * 4 + 3] = (s0 + g * 4 + 3 <= t) ? acc3 * 0.12f : -INFINITY;
    __syncthreads();

    // online softmax update (redundantly per 8 threads of a row — consistent)
    float tmax = -INFINITY;
#pragma unroll
    for (int j = 0; j < 32; ++j) tmax = fmaxf(tmax, Ss[r][j]);
    float nm = fmaxf(m, tmax);
    float alpha = __expf(m - nm);
#pragma unroll
    for (int w = 0; w < 4; ++w) {
      Of[w].x *= alpha; Of[w].y *= alpha; Of[w].z *= alpha; Of[w].w *= alpha;
    }
    float psum = 0.0f;
#pragma unroll 4
    for (int j = 0; j < 32; ++j) {
      float p = __expf(Ss[r][j] - nm);
      psum += p;
#pragma unroll
      for (int w = 0; w < 4; ++w) {
        float4 vv = *(const float4*)&Vs[j][g * 16 + w * 4];
        Of[w].x += p * vv.x; Of[w].y += p * vv.y; Of[w].z += p * vv.z; Of[w].w += p * vv.w;
      }
    }
    m = nm;
    l = l * alpha + psum;
  }

  float inv = 1.0f / l;
#pragma unroll
  for (int w = 0; w < 4; ++w) {
    float4 o;
    o.x = Of[w].x * inv; o.y = Of[w].y * inv; o.z = Of[w].z * inv; o.w = Of[w].w * inv;
    *(float4*)&y[(long)(q0 + r) * HDIM + h * DH + g * 16 + w * 4] = o;
  }
}

// ---------------------------------------------------------------------------
extern "C" void kernel_launch(void* const* d_in, const int* in_sizes, int n_in,
                              void* d_out, int out_size, void* d_ws, size_t ws_size,
                              hipStream_t stream) {
  const float* x       = (const float*)d_in[0];  // (1, 2048, 2048)
  const float* w       = (const float*)d_in[1];  // (4, 2048, 2048)
  const float* ve      = (const float*)d_in[2];  // (1, 2048, 2048)
  const float* lambdas = (const float*)d_in[3];  // (2,)
  float* out = (float*)d_out;                    // (1, 2048, 2048) fp32

  float* qkv = (float*)d_ws;                     // [3][SEQ][HDIM] = 50.3 MB
  float* y   = qkv + 3L * SEQ * HDIM;            // [SEQ][HDIM]    = 16.8 MB

  // q,k,v = x @ w[e]^T  (e = 0,1,2 via blockIdx.z)
  gemm_nt<<<dim3(32, 32, 3), 256, 0, stream>>>(x, w, qkv,
                                               (long)HDIM * CDIM, (long)SEQ * HDIM);
  // rmsnorm + rope + v-mix, in place
  norm_rope_mix<<<dim3(SEQ, NH), 64, 0, stream>>>(qkv, ve, lambdas);
  // causal attention -> y
  flash_attn<<<dim3(SEQ / 32, NH), 256, 0, stream>>>(qkv, y);
  // out = y @ w[3]^T
  gemm_nt<<<dim3(32, 32, 1), 256, 0, stream>>>(y, w + 3L * HDIM * CDIM, out, 0, 0);
}

// Round 2
// 340.697 us; speedup vs baseline: 6.4811x; 6.4811x over previous
//
#include <hip/hip_runtime.h>
#include <math.h>

#define SEQ  2048
#define CDIM 2048
#define NH   16
#define DH   128
#define HDIM 2048   // NH * DH

typedef __attribute__((ext_vector_type(8))) short  bf16x8;  // 8 bf16 = 4 VGPRs
typedef __attribute__((ext_vector_type(4))) float  f32x4;   // MFMA acc
typedef unsigned short ushort_t;

__device__ __forceinline__ unsigned short f2bf(float f) {   // RNE float->bf16
  unsigned u = __float_as_uint(f);
  u = (u + 0x7fffu + ((u >> 16) & 1u)) >> 16;
  return (unsigned short)u;
}
__device__ __forceinline__ float b2f(unsigned short s) {
  return __uint_as_float((unsigned)s << 16);
}

// async global->LDS, 16B per lane. LDS dest is wave-uniform base + lane*16.
__device__ __forceinline__ void async_ld16(const ushort_t* g, ushort_t* l) {
  __builtin_amdgcn_global_load_lds((const __attribute__((address_space(1))) unsigned int*)g,
                                   (__attribute__((address_space(3))) unsigned int*)l,
                                   16, 0, 0);
}

__device__ __forceinline__ f32x4 mfma16(bf16x8 a, bf16x8 b, f32x4 c) {
  return __builtin_amdgcn_mfma_f32_16x16x32_bf16(a, b, c, 0, 0, 0);
}

// ---------------------------------------------------------------------------
// fp32 -> bf16 pack, 8 elems/thread
// ---------------------------------------------------------------------------
__global__ __launch_bounds__(256) void to_bf16(const float* __restrict__ src,
                                               ushort_t* __restrict__ dst, int n8) {
  int i = blockIdx.x * 256 + threadIdx.x;
  if (i >= n8) return;
  const float4* s = (const float4*)src;
  float4 f0 = s[i * 2], f1 = s[i * 2 + 1];
  bf16x8 o;
  o[0] = (short)f2bf(f0.x); o[1] = (short)f2bf(f0.y);
  o[2] = (short)f2bf(f0.z); o[3] = (short)f2bf(f0.w);
  o[4] = (short)f2bf(f1.x); o[5] = (short)f2bf(f1.y);
  o[6] = (short)f2bf(f1.z); o[7] = (short)f2bf(f1.w);
  *(bf16x8*)&dst[i * 8] = o;
}

// ---------------------------------------------------------------------------
// bf16 MFMA GEMM (NT): C[m][n] = sum_k A[m][k]*B[n][k].  M=N=K=2048.
// 128x128 tile, BK=32, 256 thr (2x2 waves, 64x64/wave, 4x4 MFMA 16x16x32).
// Staging via global_load_lds w=16; XOR chunk swizzle (applied on the global
// source address, LDS stays lane-contiguous) kills the stride-64B conflicts.
// ---------------------------------------------------------------------------
template <int OUT_BF16>
__global__ __launch_bounds__(256) void gemm_bf16(const ushort_t* __restrict__ A,
                                                 const ushort_t* __restrict__ B,
                                                 void* __restrict__ Cv,
                                                 long bStride, long cStride) {
  constexpr int K = CDIM, N = HDIM;
  __shared__ __align__(16) ushort_t As[128 * 32];
  __shared__ __align__(16) ushort_t Bs[128 * 32];
  const ushort_t* Bp = B + (long)blockIdx.z * bStride;
  const int m0 = blockIdx.y * 128, n0 = blockIdx.x * 128;
  const int tid = threadIdx.x, lane = tid & 63, wave = tid >> 6;
  const int wm = wave >> 1, wn = wave & 1;
  const int g = lane >> 4, l15 = lane & 15;
  const int srow = tid >> 2, scc = tid & 3;   // staging: row, 16B-chunk

  f32x4 acc[4][4];
#pragma unroll
  for (int i = 0; i < 4; ++i)
#pragma unroll
    for (int j = 0; j < 4; ++j) acc[i][j] = (f32x4)0.0f;

  for (int k0 = 0; k0 < K; k0 += 32) {
    __syncthreads();
    {
      int r0 = srow, r1 = srow + 64;
      int c0 = scc ^ ((r0 >> 1) & 3), c1 = scc ^ ((r1 >> 1) & 3);
      async_ld16(&A [(long)(m0 + r0) * K + k0 + c0 * 8], &As[wave * 512]);
      async_ld16(&A [(long)(m0 + r1) * K + k0 + c1 * 8], &As[2048 + wave * 512]);
      async_ld16(&Bp[(long)(n0 + r0) * K + k0 + c0 * 8], &Bs[wave * 512]);
      async_ld16(&Bp[(long)(n0 + r1) * K + k0 + c1 * 8], &Bs[2048 + wave * 512]);
    }
    __syncthreads();

    bf16x8 af[4], bfr[4];
#pragma unroll
    for (int mi = 0; mi < 4; ++mi) {
      int row = wm * 64 + mi * 16 + l15;
      int cc = g ^ ((row >> 1) & 3);
      af[mi] = *(const bf16x8*)&As[row * 32 + cc * 8];
    }
#pragma unroll
    for (int ni = 0; ni < 4; ++ni) {
      int row = wn * 64 + ni * 16 + l15;
      int cc = g ^ ((row >> 1) & 3);
      bfr[ni] = *(const bf16x8*)&Bs[row * 32 + cc * 8];
    }
#pragma unroll
    for (int mi = 0; mi < 4; ++mi)
#pragma unroll
      for (int ni = 0; ni < 4; ++ni)
        acc[mi][ni] = mfma16(af[mi], bfr[ni], acc[mi][ni]);
  }

  // epilogue: D layout col=lane&15(n), row=(lane>>4)*4+reg(m)  [m89/m91]
#pragma unroll
  for (int mi = 0; mi < 4; ++mi)
#pragma unroll
    for (int ni = 0; ni < 4; ++ni) {
      int row = m0 + wm * 64 + mi * 16 + g * 4;
      int col = n0 + wn * 64 + ni * 16 + l15;
#pragma unroll
      for (int r = 0; r < 4; ++r) {
        if (OUT_BF16)
          ((ushort_t*)Cv)[cStride * blockIdx.z + (long)(row + r) * N + col] = f2bf(acc[mi][ni][r]);
        else
          ((float*)Cv)[(long)(row + r) * N + col] = acc[mi][ni][r];
      }
    }
}

// ---------------------------------------------------------------------------
// In-place RMSNorm(q,k,v) + RoPE(q,k) + v = l0*v + l1*ve on bf16 qkv.
// One wave per (t,h); thread d holds elems d and d+64 (rotate-half pair).
// ---------------------------------------------------------------------------
__device__ __forceinline__ float wave_sum64(float x) {
#pragma unroll
  for (int m = 32; m >= 1; m >>= 1) x += __shfl_xor(x, m, 64);
  return x;
}

__global__ __launch_bounds__(64) void norm_rope(ushort_t* __restrict__ qkvb,
                                                const float* __restrict__ ve,
                                                const float* __restrict__ lambdas) {
  const int t = blockIdx.x, h = blockIdx.y, d = threadIdx.x;
  const long base = (long)t * HDIM + h * DH;
  ushort_t* q = qkvb + base;
  ushort_t* k = qkvb + (long)SEQ * HDIM + base;
  ushort_t* v = qkvb + 2L * SEQ * HDIM + base;

  float q1 = b2f(q[d]), q2 = b2f(q[d + 64]);
  float k1 = b2f(k[d]), k2 = b2f(k[d + 64]);
  float v1 = b2f(v[d]), v2 = b2f(v[d + 64]);

  float qsc = rsqrtf(wave_sum64(q1 * q1 + q2 * q2) * (1.0f / 128.0f) + 1e-6f);
  float ksc = rsqrtf(wave_sum64(k1 * k1 + k2 * k2) * (1.0f / 128.0f) + 1e-6f);
  float vsc = rsqrtf(wave_sum64(v1 * v1 + v2 * v2) * (1.0f / 128.0f) + 1e-6f);
  q1 *= qsc; q2 *= qsc;
  k1 *= ksc; k2 *= ksc;
  v1 *= vsc; v2 *= vsc;

  float freq = (d < 32) ? powf(1.0f / 1024.0f, (float)d * (1.0f / 31.0f)) : 0.0f;
  float th = (float)t * freq;
  float c = cosf(th), s = sinf(th);

  float qo1 = q1 * c + q2 * s, qo2 = -q1 * s + q2 * c;
  float ko1 = k1 * c + k2 * s, ko2 = -k1 * s + k2 * c;

  float l0 = lambdas[0], l1 = lambdas[1];
  const float* vep = ve + base;
  float vo1 = l0 * v1 + l1 * vep[d];
  float vo2 = l0 * v2 + l1 * vep[d + 64];

  q[d] = f2bf(qo1); q[d + 64] = f2bf(qo2);
  k[d] = f2bf(ko1); k[d + 64] = f2bf(ko2);
  v[d] = f2bf(vo1); v[d + 64] = f2bf(vo2);
}

// ---------------------------------------------------------------------------
// v (bf16, [t][HDIM]) -> vbT ([h][d][t]) so flash can global_load_lds V-tiles.
// ---------------------------------------------------------------------------
__global__ __launch_bounds__(256) void transpose_v(const ushort_t* __restrict__ vb,
                                                   ushort_t* __restrict__ vbT) {
  __shared__ __align__(16) ushort_t L[64 * 136];
  const int t0 = blockIdx.x * 64, h = blockIdx.y;
  const int tid = threadIdx.x;
#pragma unroll
  for (int p = 0; p < 4; ++p) {
    int idx = p * 256 + tid;
    int row = idx >> 4, cc = idx & 15;
    *(bf16x8*)&L[row * 136 + cc * 8] =
        *(const bf16x8*)&vb[(long)(t0 + row) * HDIM + h * DH + cc * 8];
  }
  __syncthreads();
#pragma unroll
  for (int p = 0; p < 4; ++p) {
    int idx = p * 256 + tid;
    int d = idx >> 3, tc = (idx & 7) * 8;
    bf16x8 o;
#pragma unroll
    for (int j = 0; j < 8; ++j) o[j] = (short)L[(tc + j) * 136 + d];
    *(bf16x8*)&vbT[((long)h * DH + d) * SEQ + t0 + tc] = o;
  }
}

// ---------------------------------------------------------------------------
// MFMA flash attention. Block = 64 q-rows x 1 head, 128 thr (2 waves x 32 q).
// S^T = K·Q^T (A=K from LDS, B=Q in regs). P -> wave-private LDS -> A-layout.
// V^T staged from vbT. Online softmax per q handled in S^T C-layout via
// shfl_xor(16/32); alpha moved to O's row-lane mapping with ds_bpermute.
// ---------------------------------------------------------------------------
__global__ __launch_bounds__(128) void flash_mfma(const ushort_t* __restrict__ qkvb,
                                                  const ushort_t* __restrict__ vbT,
                                                  ushort_t* __restrict__ yb) {
  __shared__ __align__(16) ushort_t Ks[64 * 128];
  __shared__ __align__(16) ushort_t Vt[128 * 64];
  __shared__ __align__(16) ushort_t Ps[64 * 72];
  const int q0 = blockIdx.x * 64, h = blockIdx.y;
  const int tid = threadIdx.x, lane = tid & 63, wave = tid >> 6;
  const int g = lane >> 4, l15 = lane & 15;
  const ushort_t* Kg = qkvb + (long)SEQ * HDIM;
  const ushort_t* Vg = vbT + (long)h * DH * SEQ;

  // Q fragments (B-operand: B[k=d][n=q], lane n=l15, k=g*8+j), in registers
  bf16x8 qf[2][4];
#pragma unroll
  for (int nt = 0; nt < 2; ++nt)
#pragma unroll
    for (int ks = 0; ks < 4; ++ks)
      qf[nt][ks] = *(const bf16x8*)
          &qkvb[(long)(q0 + wave * 32 + nt * 16 + l15) * HDIM + h * DH + ks * 32 + g * 8];

  f32x4 oacc[2][8];
#pragma unroll
  for (int qt = 0; qt < 2; ++qt)
#pragma unroll
    for (int dt = 0; dt < 8; ++dt) oacc[qt][dt] = (f32x4)0.0f;
  float mrow[2] = {-1e30f, -1e30f}, lrow[2] = {0.0f, 0.0f};

  for (int s0 = 0; s0 <= q0; s0 += 64) {
    __syncthreads();  // prev-iter LDS reads done
#pragma unroll
    for (int i = 0; i < 8; ++i) {
      int idx = i * 128 + tid;
      { int row = idx >> 4, cc = idx & 15, cg = cc ^ (row & 7);   // K: 16 chunks/row
        async_ld16(&Kg[(long)(s0 + row) * HDIM + h * DH + cg * 8], &Ks[i * 1024 + wave * 512]); }
      { int row = idx >> 3, cc = idx & 7,  cg = cc ^ (row & 7);   // Vt: 8 chunks/row
        async_ld16(&Vg[(long)row * SEQ + s0 + cg * 8], &Vt[i * 1024 + wave * 512]); }
    }
    __syncthreads();  // drains vmcnt (global_load_lds) + barrier

    // S^T = K·Q^T : st[nt][mt], C-layout lane: q=l15(col), key=g*4+reg(row)
    f32x4 st[2][4];
#pragma unroll
    for (int nt = 0; nt < 2; ++nt)
#pragma unroll
      for (int mt = 0; mt < 4; ++mt) st[nt][mt] = (f32x4)0.0f;
#pragma unroll
    for (int ks = 0; ks < 4; ++ks)
#pragma unroll
      for (int mt = 0; mt < 4; ++mt) {
        int row = mt * 16 + l15;
        int cg = ks * 4 + g;
        int cc = cg ^ (row & 7);
        bf16x8 a = *(const bf16x8*)&Ks[row * 128 + cc * 8];
        st[0][mt] = mfma16(a, qf[0][ks], st[0][mt]);
        st[1][mt] = mfma16(a, qf[1][ks], st[1][mt]);
      }

    float alpha_q[2];
#pragma unroll
    for (int nt = 0; nt < 2; ++nt) {
      const int qg = q0 + wave * 32 + nt * 16 + l15;
      float p[4][4];
      float tmax = -1e30f;
#pragma unroll
      for (int mt = 0; mt < 4; ++mt)
#pragma unroll
        for (int r = 0; r < 4; ++r) {
          float sv = st[nt][mt][r] * 0.12f;
          if (s0 + mt * 16 + g * 4 + r > qg) sv = -1e30f;  // causal
          p[mt][r] = sv;
          tmax = fmaxf(tmax, sv);
        }
      tmax = fmaxf(tmax, __shfl_xor(tmax, 16, 64));
      tmax = fmaxf(tmax, __shfl_xor(tmax, 32, 64));
      float nm = fmaxf(mrow[nt], tmax);
      float alpha = __expf(mrow[nt] - nm);
      float psum = 0.0f;
#pragma unroll
      for (int mt = 0; mt < 4; ++mt) {
        float e0 = __expf(p[mt][0] - nm), e1 = __expf(p[mt][1] - nm);
        float e2 = __expf(p[mt][2] - nm), e3 = __expf(p[mt][3] - nm);
        unsigned short b0 = f2bf(e0), b1 = f2bf(e1), b2 = f2bf(e2), b3 = f2bf(e3);
        psum += b2f(b0) + b2f(b1) + b2f(b2) + b2f(b3);  // l consistent with bf16 P
        unsigned lo = (unsigned)b0 | ((unsigned)b1 << 16);
        unsigned hi = (unsigned)b2 | ((unsigned)b3 << 16);
        *(uint2*)&Ps[(wave * 32 + nt * 16 + l15) * 72 + mt * 16 + g * 4] = make_uint2(lo, hi);
      }
      psum += __shfl_xor(psum, 16, 64);
      psum += __shfl_xor(psum, 32, 64);
      mrow[nt] = nm;
      lrow[nt] = lrow[nt] * alpha + psum;
      alpha_q[nt] = alpha;
    }

    // rescale O: alpha is keyed by l15; O rows are keyed by g*4+reg -> bpermute
    float aO[2][4];
#pragma unroll
    for (int qt = 0; qt < 2; ++qt)
#pragma unroll
      for (int r = 0; r < 4; ++r)
        aO[qt][r] = __shfl(alpha_q[qt], g * 4 + r, 64);
#pragma unroll
    for (int qt = 0; qt < 2; ++qt)
#pragma unroll
      for (int dt = 0; dt < 8; ++dt)
#pragma unroll
        for (int r = 0; r < 4; ++r)
          oacc[qt][dt][r] *= aO[qt][r];

    // O += P·V  (A=P from wave-private Ps rows, B=V^T from Vt)
#pragma unroll
    for (int ks = 0; ks < 2; ++ks) {
      bf16x8 ap0 = *(const bf16x8*)&Ps[(wave * 32 + l15) * 72 + ks * 32 + g * 8];
      bf16x8 ap1 = *(const bf16x8*)&Ps[(wave * 32 + 16 + l15) * 72 + ks * 32 + g * 8];
#pragma unroll
      for (int dt = 0; dt < 8; ++dt) {
        int row = dt * 16 + l15;
        int cg = ks * 4 + g;
        int cc = cg ^ (row & 7);
        bf16x8 bv = *(const bf16x8*)&Vt[row * 64 + cc * 8];
        oacc[0][dt] = mfma16(ap0, bv, oacc[0][dt]);
        oacc[1][dt] = mfma16(ap1, bv, oacc[1][dt]);
      }
    }
  }

  float linv[2][4];
#pragma unroll
  for (int qt = 0; qt < 2; ++qt)
#pragma unroll
    for (int r = 0; r < 4; ++r)
      linv[qt][r] = 1.0f / __shfl(lrow[qt], g * 4 + r, 64);
#pragma unroll
  for (int qt = 0; qt < 2; ++qt)
#pragma unroll
    for (int dt = 0; dt < 8; ++dt) {
      int row = q0 + wave * 32 + qt * 16 + g * 4;
      int col = h * DH + dt * 16 + l15;
#pragma unroll
      for (int r = 0; r < 4; ++r)
        yb[(long)(row + r) * HDIM + col] = f2bf(oacc[qt][dt][r] * linv[qt][r]);
    }
}

// ---------------------------------------------------------------------------
extern "C" void kernel_launch(void* const* d_in, const int* in_sizes, int n_in,
                              void* d_out, int out_size, void* d_ws, size_t ws_size,
                              hipStream_t stream) {
  const float* x       = (const float*)d_in[0];  // (1, 2048, 2048)
  const float* w       = (const float*)d_in[1];  // (4, 2048, 2048)
  const float* ve      = (const float*)d_in[2];  // (1, 2048, 2048)
  const float* lambdas = (const float*)d_in[3];  // (2,)
  float* out = (float*)d_out;

  // ws layout (75.5 MB): qkvb 25.2M | xb 8.4M (reused as yb) | wb 33.6M | vbT 8.4M
  char* ws = (char*)d_ws;
  ushort_t* qkvb = (ushort_t*)ws;                     // [3][SEQ][HDIM] bf16
  ushort_t* xb   = (ushort_t*)(ws + 25165824);        // [SEQ][CDIM]    bf16
  ushort_t* wb   = (ushort_t*)(ws + 33554432);        // [4][HDIM][CDIM] bf16
  ushort_t* vbT  = (ushort_t*)(ws + 67108864);        // [NH][DH][SEQ]  bf16
  ushort_t* yb   = xb;  // xb dead after QKV GEMM

  to_bf16<<<2048, 256, 0, stream>>>(x, xb, (SEQ * CDIM) / 8);
  to_bf16<<<8192, 256, 0, stream>>>(w, wb, (4 * HDIM * CDIM) / 8);
  gemm_bf16<1><<<dim3(16, 16, 3), 256, 0, stream>>>(xb, wb, qkvb,
                                                    (long)HDIM * CDIM, (long)SEQ * HDIM);
  norm_rope<<<dim3(SEQ, NH), 64, 0, stream>>>(qkvb, ve, lambdas);
  transpose_v<<<dim3(SEQ / 64, NH), 256, 0, stream>>>(qkvb + 2L * SEQ * HDIM, vbT);
  flash_mfma<<<dim3(SEQ / 64, NH), 128, 0, stream>>>(qkvb, vbT, yb);
  gemm_bf16<0><<<dim3(16, 16, 1), 256, 0, stream>>>(yb, wb + 3L * HDIM * CDIM, out, 0, 0);
}